// Round 1
// baseline (1160.426 us; speedup 1.0000x reference)
//
#include <hip/hip_runtime.h>
#include <hip/hip_bf16.h>
#include <stdint.h>
#include <stddef.h>

typedef __hip_bfloat16 bf16;
typedef __attribute__((ext_vector_type(8))) short short8;
typedef __attribute__((ext_vector_type(4))) float f32x4;

#define GLDS16(g, l) __builtin_amdgcn_global_load_lds( \
    (const __attribute__((address_space(1))) void*)(g), \
    (__attribute__((address_space(3))) void*)(l), 16, 0, 0)

__device__ __forceinline__ float bf2f(bf16 x) { return __bfloat162float(x); }
__device__ __forceinline__ bf16  f2bf(float x) { return __float2bfloat16(x); }

// ================= weight convert + transpose: src [K][N] f32 -> dst [N][K] bf16 (hi[,lo]) ===============
template<bool SPLIT>
__global__ void wconv(const float* __restrict__ src, bf16* __restrict__ dhi,
                      bf16* __restrict__ dlo, int K, int N) {
  __shared__ float tile[32][33];
  const size_t zoff = (size_t)blockIdx.z * K * N;
  const float* s = src + zoff;
  const int n0 = blockIdx.x * 32, k0 = blockIdx.y * 32;
  const int tx = threadIdx.x & 31, ty = threadIdx.x >> 5;
#pragma unroll
  for (int i = 0; i < 32; i += 8)
    tile[ty + i][tx] = s[(size_t)(k0 + ty + i) * N + (n0 + tx)];
  __syncthreads();
#pragma unroll
  for (int i = 0; i < 32; i += 8) {
    const float v = tile[tx][ty + i];
    const size_t o = zoff + (size_t)(n0 + ty + i) * K + (k0 + tx);
    const bf16 h = f2bf(v);
    dhi[o] = h;
    if (SPLIT) dlo[o] = f2bf(v - bf2f(h));
  }
}

// ================= elementwise f32 -> bf16 hi/lo split =================
__global__ void splitv(const float* __restrict__ x, bf16* __restrict__ hi,
                       bf16* __restrict__ lo, int n4) {
  const int i = blockIdx.x * 256 + threadIdx.x;
  if (i >= n4) return;
  const float4 v = ((const float4*)x)[i];
  const float f[4] = {v.x, v.y, v.z, v.w};
#pragma unroll
  for (int j = 0; j < 4; ++j) {
    const bf16 h = f2bf(f[j]);
    hi[i * 4 + j] = h;
    lo[i * 4 + j] = f2bf(f[j] - bf2f(h));
  }
}

// ================= GEMM: C[M,N] = A[M,K] @ B^T (B stored [N][K]) ===============
// EPI: 0 relu -> (Ch,Cl) split out      [encoder GEMM1]
//      1 +bias +R(f32) -> (Cf,Ch,Cl)    [encoder GEMM2, residual]
//      2 +bias -> (Cf,Ch)               [encoder final Wf -> latent]
//      3 relu -> Ch                      [expert/value GEMM1]
//      4 +bias +R(bf16) -> Ch            [expert/value GEMM2, residual]
template<int EPI, bool SPLIT>
__global__ __launch_bounds__(256, 2)
void gemm_bt(const bf16* __restrict__ Ah, const bf16* __restrict__ Al, size_t aSz,
             const bf16* __restrict__ Bh, const bf16* __restrict__ Bl, size_t bSz,
             const float* __restrict__ bias, size_t biasSz,
             const void* __restrict__ R, size_t rSz,
             float* __restrict__ Cf,
             bf16* __restrict__ Ch, bf16* __restrict__ Cl, size_t cSz,
             int M, int N, int K) {
  __shared__ __align__(16) bf16 As[SPLIT ? 2 : 1][128][32];
  __shared__ __align__(16) bf16 Bs[SPLIT ? 2 : 1][128][32];

  const int z = blockIdx.z;
  Ah += (size_t)z * aSz;
  Bh += (size_t)z * bSz;
  if (SPLIT) { Al += (size_t)z * aSz; Bl += (size_t)z * bSz; }
  bias += (size_t)z * biasSz;
  Ch += (size_t)z * cSz;
  const float* Rf = (const float*)R;
  const bf16*  Rb = (const bf16*)R;
  if (EPI == 1) Rf += (size_t)z * rSz;
  if (EPI == 4) Rb += (size_t)z * rSz;

  const int tid = threadIdx.x, lane = tid & 63, wave = tid >> 6;
  const int wr = wave >> 1, wc = wave & 1;
  const int rowA0 = blockIdx.x * 128, rowB0 = blockIdx.y * 128;
  const int fr = lane & 15, kq = (lane >> 4) << 3, fq = (lane >> 4) << 2;

  f32x4 acc[4][4];
#pragma unroll
  for (int m = 0; m < 4; ++m)
#pragma unroll
    for (int n = 0; n < 4; ++n) {
      acc[m][n][0] = 0.f; acc[m][n][1] = 0.f; acc[m][n][2] = 0.f; acc[m][n][3] = 0.f;
    }

  const int nk = K >> 5;
  for (int kt = 0; kt < nk; ++kt) {
    const int k0 = kt << 5;
#pragma unroll
    for (int i = 0; i < 2; ++i) {
      const int bidx = i * 256 + wave * 64;         // wave-uniform LDS base index
      const int idx  = bidx + lane;                 // per-lane global index
      const int row = idx >> 2, seg = (idx & 3) << 3;
      const size_t ga = (size_t)(rowA0 + row) * K + k0 + seg;
      const size_t gb = (size_t)(rowB0 + row) * K + k0 + seg;
      GLDS16(Ah + ga, &As[0][0][0] + (size_t)bidx * 8);
      GLDS16(Bh + gb, &Bs[0][0][0] + (size_t)bidx * 8);
      if (SPLIT) {
        GLDS16(Al + ga, &As[SPLIT ? 1 : 0][0][0] + (size_t)bidx * 8);
        GLDS16(Bl + gb, &Bs[SPLIT ? 1 : 0][0][0] + (size_t)bidx * 8);
      }
    }
    __syncthreads();

    short8 a0[4], b0[4];
#pragma unroll
    for (int m = 0; m < 4; ++m)
      a0[m] = *(const short8*)&As[0][wr * 64 + m * 16 + fr][kq];
#pragma unroll
    for (int n = 0; n < 4; ++n)
      b0[n] = *(const short8*)&Bs[0][wc * 64 + n * 16 + fr][kq];

    if (SPLIT) {
      short8 a1[4], b1[4];
#pragma unroll
      for (int m = 0; m < 4; ++m)
        a1[m] = *(const short8*)&As[SPLIT ? 1 : 0][wr * 64 + m * 16 + fr][kq];
#pragma unroll
      for (int n = 0; n < 4; ++n)
        b1[n] = *(const short8*)&Bs[SPLIT ? 1 : 0][wc * 64 + n * 16 + fr][kq];
#pragma unroll
      for (int m = 0; m < 4; ++m)
#pragma unroll
        for (int n = 0; n < 4; ++n) {
          acc[m][n] = __builtin_amdgcn_mfma_f32_16x16x32_bf16(a1[m], b0[n], acc[m][n], 0, 0, 0);
          acc[m][n] = __builtin_amdgcn_mfma_f32_16x16x32_bf16(a0[m], b1[n], acc[m][n], 0, 0, 0);
        }
    }
#pragma unroll
    for (int m = 0; m < 4; ++m)
#pragma unroll
      for (int n = 0; n < 4; ++n)
        acc[m][n] = __builtin_amdgcn_mfma_f32_16x16x32_bf16(a0[m], b0[n], acc[m][n], 0, 0, 0);
    __syncthreads();
  }

  // epilogue
#pragma unroll
  for (int n = 0; n < 4; ++n) {
    const int col = blockIdx.y * 128 + wc * 64 + n * 16 + fr;
    const float bv = bias[col];
#pragma unroll
    for (int m = 0; m < 4; ++m) {
      const int row0 = blockIdx.x * 128 + wr * 64 + m * 16 + fq;
#pragma unroll
      for (int r = 0; r < 4; ++r) {
        const size_t o = (size_t)(row0 + r) * N + col;
        float v = acc[m][n][r] + bv;
        if (EPI == 0 || EPI == 3) v = fmaxf(v, 0.f);
        if (EPI == 1) v += Rf[o];
        if (EPI == 4) v += bf2f(Rb[o]);
        if (EPI == 1 || EPI == 2) Cf[o] = v;
        const bf16 h = f2bf(v);
        Ch[o] = h;
        if (EPI == 0 || EPI == 1) Cl[o] = f2bf(v - bf2f(h));
      }
    }
  }
}

// ================= gating: logits = latent @ w_gate; top-2 softmax scatter ===============
__global__ void gate_topk(const float* __restrict__ latent, const float* __restrict__ wg,
                          float* __restrict__ gates) {
  const int b = blockIdx.x * 4 + (threadIdx.x >> 6);
  const int lane = threadIdx.x & 63;
  const int e = lane >> 3, j = lane & 7;
  const float* L = latent + (size_t)b * 512;
  float s = 0.f;
  for (int k = j; k < 512; k += 8) s = fmaf(L[k], wg[k * 8 + e], s);
  s += __shfl_xor(s, 1);
  s += __shfl_xor(s, 2);
  s += __shfl_xor(s, 4);
  float lg[8];
#pragma unroll
  for (int t = 0; t < 8; ++t) lg[t] = __shfl(s, t * 8);
  if (lane == 0) {
    int i1 = 0; float v1 = lg[0];
#pragma unroll
    for (int t = 1; t < 8; ++t) if (lg[t] > v1) { v1 = lg[t]; i1 = t; }
    int i2 = -1; float v2 = -3.4e38f;
#pragma unroll
    for (int t = 0; t < 8; ++t) if (t != i1 && lg[t] > v2) { v2 = lg[t]; i2 = t; }
    const float e2 = expf(v2 - v1);
    const float inv = 1.f / (1.f + e2);
    float g[8];
#pragma unroll
    for (int t = 0; t < 8; ++t) g[t] = 0.f;
    g[i1] = inv; g[i2] = e2 * inv;
#pragma unroll
    for (int t = 0; t < 8; ++t) gates[(size_t)b * 8 + t] = g[t];
  }
}

// ================= combine: y[b,:] = sum_e g[b,e]*(He[e,b,:]@Wf_e + bf_e) ===============
__global__ void combine_out(const bf16* __restrict__ He, const float* __restrict__ Wf,
                            const float* __restrict__ Bf, const float* __restrict__ gates,
                            float* __restrict__ out) {
  const int b = blockIdx.x * 4 + (threadIdx.x >> 6);
  const int lane = threadIdx.x & 63;
  float y[19], yb[19];
#pragma unroll
  for (int o = 0; o < 19; ++o) { y[o] = 0.f; yb[o] = 0.f; }
  for (int ex = 0; ex < 8; ++ex) {
    const float g = gates[(size_t)b * 8 + ex];
    if (g == 0.f) continue;
    const bf16* h = He + ((size_t)ex * 4096 + b) * 512;
    float part[19];
#pragma unroll
    for (int o = 0; o < 19; ++o) part[o] = 0.f;
    for (int k = lane; k < 512; k += 64) {
      const float hv = bf2f(h[k]);
      const float* w = Wf + ((size_t)ex * 512 + k) * 19;
#pragma unroll
      for (int o = 0; o < 19; ++o) part[o] = fmaf(hv, w[o], part[o]);
    }
#pragma unroll
    for (int o = 0; o < 19; ++o) y[o] = fmaf(g, part[o], y[o]);
#pragma unroll
    for (int o = 0; o < 19; ++o) yb[o] = fmaf(g, Bf[ex * 19 + o], yb[o]);
  }
#pragma unroll
  for (int o = 0; o < 19; ++o) {
#pragma unroll
    for (int d = 32; d > 0; d >>= 1) y[o] += __shfl_down(y[o], d);
  }
  if (lane == 0) {
#pragma unroll
    for (int o = 0; o < 19; ++o) {
      float v = y[o] + yb[o];
      if (v == 0.f) v = 2.2204460492503131e-16f;
      out[(size_t)b * 20 + o] = v;
    }
  }
}

// ================= value head: v[b] = Hv[b,:]@Wf + bf ===============
__global__ void value_out(const bf16* __restrict__ Hv, const float* __restrict__ Wf,
                          const float* __restrict__ Bf, float* __restrict__ out) {
  const int b = blockIdx.x * 4 + (threadIdx.x >> 6);
  const int lane = threadIdx.x & 63;
  const bf16* h = Hv + (size_t)b * 1024;
  float s = 0.f;
  for (int k = lane; k < 1024; k += 64) s = fmaf(bf2f(h[k]), Wf[k], s);
#pragma unroll
  for (int d = 32; d > 0; d >>= 1) s += __shfl_down(s, d);
  if (lane == 0) out[(size_t)b * 20 + 19] = s + Bf[0];
}

// ================= host =================
extern "C" void kernel_launch(void* const* d_in, const int* in_sizes, int n_in,
                              void* d_out, int out_size, void* d_ws, size_t ws_size,
                              hipStream_t stream) {
  (void)in_sizes; (void)n_in; (void)out_size; (void)ws_size;
  const int Btok = 4096;

  const float* obs   = (const float*)d_in[0];
  const float* encW1 = (const float*)d_in[1];
  const float* encB1 = (const float*)d_in[2];
  const float* encW2 = (const float*)d_in[3];
  const float* encB2 = (const float*)d_in[4];
  const float* encWf = (const float*)d_in[5];
  const float* encBf = (const float*)d_in[6];
  const float* expW1 = (const float*)d_in[7];
  const float* expB1 = (const float*)d_in[8];
  const float* expW2 = (const float*)d_in[9];
  const float* expB2 = (const float*)d_in[10];
  const float* expWf = (const float*)d_in[11];
  const float* expBf = (const float*)d_in[12];
  const float* valW1 = (const float*)d_in[13];
  const float* valB1 = (const float*)d_in[14];
  const float* valW2 = (const float*)d_in[15];
  const float* valB2 = (const float*)d_in[16];
  const float* valWf = (const float*)d_in[17];
  const float* valBf = (const float*)d_in[18];
  const float* wgate = (const float*)d_in[19];

  char* p = (char*)d_ws;
  auto alloc = [&](size_t bytes) -> char* {
    char* r = p; p += (bytes + 255) & ~(size_t)255; return r;
  };
  // weights (bf16, transposed [N][K])
  bf16* encW1tH = (bf16*)alloc((size_t)3 * 1024 * 1024 * 2);
  bf16* encW1tL = (bf16*)alloc((size_t)3 * 1024 * 1024 * 2);
  bf16* encW2tH = (bf16*)alloc((size_t)3 * 1024 * 1024 * 2);
  bf16* encW2tL = (bf16*)alloc((size_t)3 * 1024 * 1024 * 2);
  bf16* encWftH = (bf16*)alloc((size_t)512 * 1024 * 2);
  bf16* encWftL = (bf16*)alloc((size_t)512 * 1024 * 2);
  bf16* valW1t  = (bf16*)alloc((size_t)3 * 1024 * 1024 * 2);
  bf16* valW2t  = (bf16*)alloc((size_t)3 * 1024 * 1024 * 2);
  bf16* expW1t  = (bf16*)alloc((size_t)24 * 512 * 1024 * 2);
  bf16* expW2t  = (bf16*)alloc((size_t)24 * 512 * 1024 * 2);
  // activations
  bf16*  obsH  = (bf16*)alloc((size_t)Btok * 1024 * 2);
  bf16*  tH    = (bf16*)alloc((size_t)Btok * 1024 * 2);
  bf16*  hH    = (bf16*)alloc((size_t)Btok * 1024 * 2);
  float* latF  = (float*)alloc((size_t)Btok * 512 * 4);
  bf16*  latB  = (bf16*)alloc((size_t)Btok * 512 * 2);
  bf16*  He    = (bf16*)alloc((size_t)8 * Btok * 512 * 2);
  float* gates = (float*)alloc((size_t)Btok * 8 * 4);
  // region X: encoder split temporaries; reused as Te by experts (enc-only bufs dead by then)
  char* X = alloc((size_t)8 * Btok * 1024 * 2);  // 64 MiB
  bf16*  obsL = (bf16*)X;
  bf16*  tL   = (bf16*)(X + (size_t)Btok * 1024 * 2);
  float* hF   = (float*)(X + (size_t)2 * Btok * 1024 * 2);
  bf16*  hL   = (bf16*)(X + (size_t)2 * Btok * 1024 * 2 + (size_t)Btok * 1024 * 4);
  bf16*  Te   = (bf16*)X;

  const dim3 blk(256);

  // --- conversions ---
  splitv<<<dim3((Btok * 1024 / 4 + 255) / 256), blk, 0, stream>>>(obs, obsH, obsL, Btok * 1024 / 4);
  wconv<true ><<<dim3(32, 32, 3),  blk, 0, stream>>>(encW1, encW1tH, encW1tL, 1024, 1024);
  wconv<true ><<<dim3(32, 32, 3),  blk, 0, stream>>>(encW2, encW2tH, encW2tL, 1024, 1024);
  wconv<true ><<<dim3(16, 32, 1),  blk, 0, stream>>>(encWf, encWftH, encWftL, 1024, 512);
  wconv<false><<<dim3(32, 32, 3),  blk, 0, stream>>>(valW1, valW1t, nullptr, 1024, 1024);
  wconv<false><<<dim3(32, 32, 3),  blk, 0, stream>>>(valW2, valW2t, nullptr, 1024, 1024);
  wconv<false><<<dim3(32, 16, 24), blk, 0, stream>>>(expW1, expW1t, nullptr, 512, 1024);
  wconv<false><<<dim3(16, 32, 24), blk, 0, stream>>>(expW2, expW2t, nullptr, 1024, 512);

  // --- encoder (split bf16, f32 residual stream) ---
  {
    const bf16* aH = obsH; const bf16* aL = obsL; const float* resF = obs;
    for (int bi = 0; bi < 3; ++bi) {
      gemm_bt<0, true><<<dim3(32, 8, 1), blk, 0, stream>>>(
          aH, aL, 0, encW1tH + (size_t)bi * 1024 * 1024, encW1tL + (size_t)bi * 1024 * 1024, 0,
          encB1 + bi * 1024, 0, nullptr, 0, nullptr, tH, tL, 0, Btok, 1024, 1024);
      gemm_bt<1, true><<<dim3(32, 8, 1), blk, 0, stream>>>(
          tH, tL, 0, encW2tH + (size_t)bi * 1024 * 1024, encW2tL + (size_t)bi * 1024 * 1024, 0,
          encB2 + bi * 1024, 0, resF, 0, hF, hH, hL, 0, Btok, 1024, 1024);
      aH = hH; aL = hL; resF = hF;
    }
    gemm_bt<2, true><<<dim3(32, 4, 1), blk, 0, stream>>>(
        hH, hL, 0, encWftH, encWftL, 0, encBf, 0, nullptr, 0, latF, latB, nullptr, 0,
        Btok, 512, 1024);
  }

  gate_topk<<<dim3(1024), blk, 0, stream>>>(latF, wgate, gates);

  // --- experts (batched over z=8, plain bf16; overwrites region X as Te) ---
  {
    const size_t sW1 = (size_t)512 * 1024, sW2 = (size_t)1024 * 512;
    const size_t sTe = (size_t)Btok * 1024, sHe = (size_t)Btok * 512;
    for (int bi = 0; bi < 3; ++bi) {
      const bf16* a = (bi == 0) ? latB : He;
      const size_t aSz = (bi == 0) ? 0 : sHe;
      gemm_bt<3, false><<<dim3(32, 8, 8), blk, 0, stream>>>(
          a, nullptr, aSz, expW1t + bi * sW1, nullptr, 3 * sW1,
          expB1 + bi * 1024, 3 * 1024, nullptr, 0, nullptr, Te, nullptr, sTe,
          Btok, 1024, 512);
      gemm_bt<4, false><<<dim3(32, 4, 8), blk, 0, stream>>>(
          Te, nullptr, sTe, expW2t + bi * sW2, nullptr, 3 * sW2,
          expB2 + bi * 512, 3 * 512,
          (bi == 0) ? (const void*)latB : (const void*)He, (size_t)((bi == 0) ? 0 : sHe),
          nullptr, He, nullptr, sHe, Btok, 512, 1024);
    }
  }
  combine_out<<<dim3(1024), blk, 0, stream>>>(He, expWf, expBf, gates, (float*)d_out);

  // --- value head (plain bf16; reuses tH/hH, obsH as block-0 input/residual) ---
  {
    const bf16* av = obsH; const bf16* resV = obsH;
    for (int bi = 0; bi < 3; ++bi) {
      gemm_bt<3, false><<<dim3(32, 8, 1), blk, 0, stream>>>(
          av, nullptr, 0, valW1t + (size_t)bi * 1024 * 1024, nullptr, 0,
          valB1 + bi * 1024, 0, nullptr, 0, nullptr, tH, nullptr, 0, Btok, 1024, 1024);
      gemm_bt<4, false><<<dim3(32, 8, 1), blk, 0, stream>>>(
          tH, nullptr, 0, valW2t + (size_t)bi * 1024 * 1024, nullptr, 0,
          valB2 + bi * 1024, 0, resV, 0, nullptr, hH, nullptr, 0, Btok, 1024, 1024);
      av = hH; resV = hH;
    }
    value_out<<<dim3(1024), blk, 0, stream>>>(hH, valWf, valBf, (float*)d_out);
  }
}

// Round 2
// 1021.229 us; speedup vs baseline: 1.1363x; 1.1363x over previous
//
#include <hip/hip_runtime.h>
#include <hip/hip_bf16.h>
#include <stdint.h>
#include <stddef.h>

typedef __hip_bfloat16 bf16;
typedef __attribute__((ext_vector_type(8))) short short8;
typedef __attribute__((ext_vector_type(4))) float f32x4;

#define GLDS16(g, l) __builtin_amdgcn_global_load_lds( \
    (const __attribute__((address_space(1))) void*)(g), \
    (__attribute__((address_space(3))) void*)(l), 16, 0, 0)

__device__ __forceinline__ float bf2f(bf16 x) { return __bfloat162float(x); }
__device__ __forceinline__ bf16  f2bf(float x) { return __float2bfloat16(x); }

constexpr int CAP = 4096;   // per-expert token capacity (worst case)

// ================= weight convert + transpose: src [K][N] f32 -> dst [N][K] bf16 (hi[,lo]) ===============
template<bool SPLIT>
__global__ void wconv(const float* __restrict__ src, bf16* __restrict__ dhi,
                      bf16* __restrict__ dlo, int K, int N) {
  __shared__ float tile[32][33];
  const size_t zoff = (size_t)blockIdx.z * K * N;
  const float* s = src + zoff;
  const int n0 = blockIdx.x * 32, k0 = blockIdx.y * 32;
  const int tx = threadIdx.x & 31, ty = threadIdx.x >> 5;
#pragma unroll
  for (int i = 0; i < 32; i += 8)
    tile[ty + i][tx] = s[(size_t)(k0 + ty + i) * N + (n0 + tx)];
  __syncthreads();
#pragma unroll
  for (int i = 0; i < 32; i += 8) {
    const float v = tile[tx][ty + i];
    const size_t o = zoff + (size_t)(n0 + ty + i) * K + (k0 + tx);
    const bf16 h = f2bf(v);
    dhi[o] = h;
    if (SPLIT) dlo[o] = f2bf(v - bf2f(h));
  }
}

// ================= elementwise f32 -> bf16 hi/lo split =================
__global__ void splitv(const float* __restrict__ x, bf16* __restrict__ hi,
                       bf16* __restrict__ lo, int n4) {
  const int i = blockIdx.x * 256 + threadIdx.x;
  if (i >= n4) return;
  const float4 v = ((const float4*)x)[i];
  const float f[4] = {v.x, v.y, v.z, v.w};
#pragma unroll
  for (int j = 0; j < 4; ++j) {
    const bf16 h = f2bf(f[j]);
    hi[i * 4 + j] = h;
    lo[i * 4 + j] = f2bf(f[j] - bf2f(h));
  }
}

// ================= GEMM: C[M,N] = A[M,K] @ B^T (B stored [N][K]) ===============
// BK=64, XOR-swizzled LDS (both-sides), 1D grid with bijective XCD swizzle.
// EPI: 0 relu -> (Ch,Cl)                 [encoder GEMM1]
//      1 +bias +Rh+Rl(bf16 pair) -> (Ch,Cl)  [encoder GEMM2]
//      2 +bias -> (Cf,Ch)                [encoder final -> latent]
//      3 relu -> Ch                      [expert/value GEMM1]
//      4 +bias +R(bf16) -> Ch            [expert/value GEMM2]
//      5 +bias +R(bf16, perm-gathered rows) -> Ch   [expert GEMM2, layer 0]
// GATHER: A rows indirected through perm (expert GEMM1, layer 0)
// cnt != nullptr: early-exit blocks with bx*128 >= cnt[bz]
template<int EPI, bool SPLIT, bool GATHER>
__global__ __launch_bounds__(256, 2)
void gemm_bt(const bf16* __restrict__ Ah, const bf16* __restrict__ Al, size_t aSz,
             const bf16* __restrict__ Bh, const bf16* __restrict__ Bl, size_t bSz,
             const float* __restrict__ bias, size_t biasSz,
             const void* __restrict__ R, const void* __restrict__ R2, size_t rSz,
             float* __restrict__ Cf, bf16* __restrict__ Ch, bf16* __restrict__ Cl, size_t cSz,
             const int* __restrict__ perm, const int* __restrict__ cnt,
             int M, int N, int K) {
  __shared__ __align__(16) bf16 As[(SPLIT ? 2 : 1) * 128 * 64];
  __shared__ __align__(16) bf16 Bs[(SPLIT ? 2 : 1) * 128 * 64];

  const int gx = M >> 7, gy = N >> 7;
  const int nwg = gridDim.x;
  const int lid = blockIdx.x;
  const int wid = (lid & 7) * (nwg >> 3) + (lid >> 3);   // bijective XCD swizzle (nwg%8==0)
  const int by = wid % gy;                                // by fastest: A-panel reuse per XCD
  const int bx = (wid / gy) % gx;
  const int bz = wid / (gy * gx);

  int cE = 0x7fffffff;
  if (cnt) { cE = cnt[bz]; if (bx * 128 >= cE) return; }

  Ah += (size_t)bz * aSz;
  Bh += (size_t)bz * bSz;
  if (SPLIT) { Al += (size_t)bz * aSz; Bl += (size_t)bz * bSz; }
  bias += (size_t)bz * biasSz;
  Ch += (size_t)bz * cSz;
  const bf16* Rb = (const bf16*)R;
  const bf16* Rl2 = (const bf16*)R2;
  if (EPI == 4) Rb += (size_t)bz * rSz;
  const int* permz = perm ? (perm + (size_t)bz * CAP) : nullptr;

  const int tid = threadIdx.x, lane = tid & 63, wave = tid >> 6;
  const int wr = wave >> 1, wc = wave & 1;
  const int fr = lane & 15, q = lane >> 4, fq = q << 2;

  // staging row indices (fixed across K-loop)
  int arow[4], brow[4];
#pragma unroll
  for (int i = 0; i < 4; ++i) {
    const int r = (i * 256 + tid) >> 3;
    const int slot = bx * 128 + r;
    arow[i] = GATHER ? ((slot < cE) ? permz[slot] : 0) : slot;
    brow[i] = by * 128 + r;
  }

  f32x4 acc[4][4];
#pragma unroll
  for (int m = 0; m < 4; ++m)
#pragma unroll
    for (int n = 0; n < 4; ++n) {
      acc[m][n][0] = 0.f; acc[m][n][1] = 0.f; acc[m][n][2] = 0.f; acc[m][n][3] = 0.f;
    }

  const int nk = K >> 6;
  for (int kt = 0; kt < nk; ++kt) {
    const int k0 = kt << 6;
#pragma unroll
    for (int i = 0; i < 4; ++i) {
      const int ci = i * 256 + tid;
      const int r = ci >> 3, pch = ci & 7;
      const int c = pch ^ (r & 7);                  // inverse-swizzled global chunk
      const size_t ga = (size_t)arow[i] * K + k0 + c * 8;
      const size_t gb = (size_t)brow[i] * K + k0 + c * 8;
      GLDS16(Ah + ga, As + ci * 8);
      GLDS16(Bh + gb, Bs + ci * 8);
      if (SPLIT) {
        GLDS16(Al + ga, As + 8192 + ci * 8);
        GLDS16(Bl + gb, Bs + 8192 + ci * 8);
      }
    }
    __syncthreads();

#pragma unroll
    for (int kk = 0; kk < 2; ++kk) {
      // swizzled fragment read: logical chunk (kk*4+q) ^ (row&7)
      auto LD = [&](const bf16* base, int r) -> short8 {
        const int c = ((kk << 2) + q) ^ (r & 7);
        return *(const short8*)(base + r * 64 + c * 8);
      };
      short8 a0[4], b0[4];
#pragma unroll
      for (int m = 0; m < 4; ++m) a0[m] = LD(As, wr * 64 + m * 16 + fr);
#pragma unroll
      for (int n = 0; n < 4; ++n) b0[n] = LD(Bs, wc * 64 + n * 16 + fr);
      if (SPLIT) {
        short8 a1[4], b1[4];
#pragma unroll
        for (int m = 0; m < 4; ++m) a1[m] = LD(As + 8192, wr * 64 + m * 16 + fr);
#pragma unroll
        for (int n = 0; n < 4; ++n) b1[n] = LD(Bs + 8192, wc * 64 + n * 16 + fr);
#pragma unroll
        for (int m = 0; m < 4; ++m)
#pragma unroll
          for (int n = 0; n < 4; ++n) {
            acc[m][n] = __builtin_amdgcn_mfma_f32_16x16x32_bf16(a1[m], b0[n], acc[m][n], 0, 0, 0);
            acc[m][n] = __builtin_amdgcn_mfma_f32_16x16x32_bf16(a0[m], b1[n], acc[m][n], 0, 0, 0);
          }
      }
#pragma unroll
      for (int m = 0; m < 4; ++m)
#pragma unroll
        for (int n = 0; n < 4; ++n)
          acc[m][n] = __builtin_amdgcn_mfma_f32_16x16x32_bf16(a0[m], b0[n], acc[m][n], 0, 0, 0);
    }
    __syncthreads();
  }

  // epilogue
#pragma unroll
  for (int n = 0; n < 4; ++n) {
    const int col = by * 128 + wc * 64 + n * 16 + fr;
    const float bv = bias[col];
#pragma unroll
    for (int m = 0; m < 4; ++m) {
      const int row0 = bx * 128 + wr * 64 + m * 16 + fq;
#pragma unroll
      for (int r = 0; r < 4; ++r) {
        const int rowi = row0 + r;
        const size_t o = (size_t)rowi * N + col;
        float v = acc[m][n][r] + bv;
        if (EPI == 0 || EPI == 3) v = fmaxf(v, 0.f);
        if (EPI == 1) v += bf2f(Rb[o]) + bf2f(Rl2[o]);
        if (EPI == 4) v += bf2f(Rb[o]);
        if (EPI == 5) {
          const int rr = (rowi < cE) ? permz[rowi] : 0;
          v += bf2f(Rb[(size_t)rr * N + col]);
        }
        if (EPI == 2) Cf[o] = v;
        const bf16 h = f2bf(v);
        Ch[o] = h;
        if (EPI == 0 || EPI == 1) Cl[o] = f2bf(v - bf2f(h));
      }
    }
  }
}

// ================= gating: logits = latent @ w_gate; top-2 softmax; build dispatch lists ===============
__global__ void gate_topk(const float* __restrict__ latent, const float* __restrict__ wg,
                          int* __restrict__ perm, int* __restrict__ cnt,
                          int4* __restrict__ tokES, float2* __restrict__ tokG) {
  const int b = blockIdx.x * 4 + (threadIdx.x >> 6);
  const int lane = threadIdx.x & 63;
  const int e = lane >> 3, j = lane & 7;
  const float* L = latent + (size_t)b * 512;
  float s = 0.f;
  for (int k = j; k < 512; k += 8) s = fmaf(L[k], wg[k * 8 + e], s);
  s += __shfl_xor(s, 1);
  s += __shfl_xor(s, 2);
  s += __shfl_xor(s, 4);
  float lg[8];
#pragma unroll
  for (int t = 0; t < 8; ++t) lg[t] = __shfl(s, t * 8);
  if (lane == 0) {
    int i1 = 0; float v1 = lg[0];
#pragma unroll
    for (int t = 1; t < 8; ++t) if (lg[t] > v1) { v1 = lg[t]; i1 = t; }
    int i2 = -1; float v2 = -3.4e38f;
#pragma unroll
    for (int t = 0; t < 8; ++t) if (t != i1 && lg[t] > v2) { v2 = lg[t]; i2 = t; }
    const float e2 = expf(v2 - v1);
    const float inv = 1.f / (1.f + e2);
    const int s1 = atomicAdd(&cnt[i1], 1);
    const int s2 = atomicAdd(&cnt[i2], 1);
    perm[i1 * CAP + s1] = b;
    perm[i2 * CAP + s2] = b;
    tokES[b] = make_int4(i1, s1, i2, s2);
    tokG[b] = make_float2(inv, e2 * inv);
  }
}

// ================= combine: y[b,:] = sum over the 2 dispatched experts ===============
__global__ void combine_out(const bf16* __restrict__ He, const float* __restrict__ Wf,
                            const float* __restrict__ Bf, const int4* __restrict__ tokES,
                            const float2* __restrict__ tokG, float* __restrict__ out) {
  const int b = blockIdx.x * 4 + (threadIdx.x >> 6);
  const int lane = threadIdx.x & 63;
  const int4 es = tokES[b];
  const float2 gg = tokG[b];
  float y[19];
#pragma unroll
  for (int o = 0; o < 19; ++o) y[o] = 0.f;
#pragma unroll
  for (int t = 0; t < 2; ++t) {
    const int ex = t ? es.z : es.x;
    const int sl = t ? es.w : es.y;
    const float g = t ? gg.y : gg.x;
    const bf16* h = He + ((size_t)ex * CAP + sl) * 512;
    float part[19];
#pragma unroll
    for (int o = 0; o < 19; ++o) part[o] = 0.f;
    for (int k = lane; k < 512; k += 64) {
      const float hv = bf2f(h[k]);
      const float* w = Wf + ((size_t)ex * 512 + k) * 19;
#pragma unroll
      for (int o = 0; o < 19; ++o) part[o] = fmaf(hv, w[o], part[o]);
    }
#pragma unroll
    for (int o = 0; o < 19; ++o) y[o] = fmaf(g, part[o], y[o]);
  }
#pragma unroll
  for (int o = 0; o < 19; ++o) {
#pragma unroll
    for (int d = 32; d > 0; d >>= 1) y[o] += __shfl_down(y[o], d);
  }
  if (lane == 0) {
#pragma unroll
    for (int o = 0; o < 19; ++o) {
      float v = y[o] + gg.x * Bf[es.x * 19 + o] + gg.y * Bf[es.z * 19 + o];
      if (v == 0.f) v = 2.2204460492503131e-16f;
      out[(size_t)b * 20 + o] = v;
    }
  }
}

// ================= value head: v[b] = Hv[b,:]@Wf + bf ===============
__global__ void value_out(const bf16* __restrict__ Hv, const float* __restrict__ Wf,
                          const float* __restrict__ Bf, float* __restrict__ out) {
  const int b = blockIdx.x * 4 + (threadIdx.x >> 6);
  const int lane = threadIdx.x & 63;
  const bf16* h = Hv + (size_t)b * 1024;
  float s = 0.f;
  for (int k = lane; k < 1024; k += 64) s = fmaf(bf2f(h[k]), Wf[k], s);
#pragma unroll
  for (int d = 32; d > 0; d >>= 1) s += __shfl_down(s, d);
  if (lane == 0) out[(size_t)b * 20 + 19] = s + Bf[0];
}

// ================= host =================
extern "C" void kernel_launch(void* const* d_in, const int* in_sizes, int n_in,
                              void* d_out, int out_size, void* d_ws, size_t ws_size,
                              hipStream_t stream) {
  (void)in_sizes; (void)n_in; (void)out_size; (void)ws_size;
  const int Btok = 4096;

  const float* obs   = (const float*)d_in[0];
  const float* encW1 = (const float*)d_in[1];
  const float* encB1 = (const float*)d_in[2];
  const float* encW2 = (const float*)d_in[3];
  const float* encB2 = (const float*)d_in[4];
  const float* encWf = (const float*)d_in[5];
  const float* encBf = (const float*)d_in[6];
  const float* expW1 = (const float*)d_in[7];
  const float* expB1 = (const float*)d_in[8];
  const float* expW2 = (const float*)d_in[9];
  const float* expB2 = (const float*)d_in[10];
  const float* expWf = (const float*)d_in[11];
  const float* expBf = (const float*)d_in[12];
  const float* valW1 = (const float*)d_in[13];
  const float* valB1 = (const float*)d_in[14];
  const float* valW2 = (const float*)d_in[15];
  const float* valB2 = (const float*)d_in[16];
  const float* valWf = (const float*)d_in[17];
  const float* valBf = (const float*)d_in[18];
  const float* wgate = (const float*)d_in[19];

  char* p = (char*)d_ws;
  auto alloc = [&](size_t bytes) -> char* {
    char* r = p; p += (bytes + 255) & ~(size_t)255; return r;
  };
  // weights (bf16, transposed [N][K])
  bf16* encW1tH = (bf16*)alloc((size_t)3 * 1024 * 1024 * 2);
  bf16* encW1tL = (bf16*)alloc((size_t)3 * 1024 * 1024 * 2);
  bf16* encW2tH = (bf16*)alloc((size_t)3 * 1024 * 1024 * 2);
  bf16* encW2tL = (bf16*)alloc((size_t)3 * 1024 * 1024 * 2);
  bf16* encWftH = (bf16*)alloc((size_t)512 * 1024 * 2);
  bf16* encWftL = (bf16*)alloc((size_t)512 * 1024 * 2);
  bf16* valW1t  = (bf16*)alloc((size_t)3 * 1024 * 1024 * 2);
  bf16* valW2t  = (bf16*)alloc((size_t)3 * 1024 * 1024 * 2);
  bf16* expW1t  = (bf16*)alloc((size_t)24 * 512 * 1024 * 2);
  bf16* expW2t  = (bf16*)alloc((size_t)24 * 512 * 1024 * 2);
  // activations
  bf16*  obsH  = (bf16*)alloc((size_t)Btok * 1024 * 2);
  bf16*  tH    = (bf16*)alloc((size_t)Btok * 1024 * 2);
  bf16*  hH    = (bf16*)alloc((size_t)Btok * 1024 * 2);
  float* latF  = (float*)alloc((size_t)Btok * 512 * 4);
  bf16*  latB  = (bf16*)alloc((size_t)Btok * 512 * 2);
  bf16*  He    = (bf16*)alloc((size_t)8 * CAP * 512 * 2);
  int*   perm  = (int*)alloc((size_t)8 * CAP * 4);
  int*   cnt   = (int*)alloc(8 * 4);
  int4*  tokES = (int4*)alloc((size_t)Btok * 16);
  float2* tokG = (float2*)alloc((size_t)Btok * 8);
  // region X: encoder temporaries, then expert intermediate Te
  char* X = alloc((size_t)8 * CAP * 1024 * 2);  // 64 MiB
  bf16* obsL = (bf16*)X;
  bf16* tL   = (bf16*)(X + (size_t)Btok * 1024 * 2);
  bf16* hL   = (bf16*)(X + (size_t)2 * Btok * 1024 * 2);
  bf16* Te   = (bf16*)X;

  const dim3 blk(256);

  hipMemsetAsync(cnt, 0, 8 * 4, stream);

  // --- conversions ---
  splitv<<<dim3((Btok * 1024 / 4 + 255) / 256), blk, 0, stream>>>(obs, obsH, obsL, Btok * 1024 / 4);
  wconv<true ><<<dim3(32, 32, 3),  blk, 0, stream>>>(encW1, encW1tH, encW1tL, 1024, 1024);
  wconv<true ><<<dim3(32, 32, 3),  blk, 0, stream>>>(encW2, encW2tH, encW2tL, 1024, 1024);
  wconv<true ><<<dim3(16, 32, 1),  blk, 0, stream>>>(encWf, encWftH, encWftL, 1024, 512);
  wconv<false><<<dim3(32, 32, 3),  blk, 0, stream>>>(valW1, valW1t, nullptr, 1024, 1024);
  wconv<false><<<dim3(32, 32, 3),  blk, 0, stream>>>(valW2, valW2t, nullptr, 1024, 1024);
  wconv<false><<<dim3(32, 16, 24), blk, 0, stream>>>(expW1, expW1t, nullptr, 512, 1024);
  wconv<false><<<dim3(16, 32, 24), blk, 0, stream>>>(expW2, expW2t, nullptr, 1024, 512);

  // --- encoder (split bf16, bf16-pair residual stream) ---
  {
    const bf16 *aH = obsH, *aL = obsL, *rH = obsH, *rL = obsL;
    for (int bi = 0; bi < 3; ++bi) {
      gemm_bt<0, true, false><<<dim3(256), blk, 0, stream>>>(
          aH, aL, 0, encW1tH + (size_t)bi * 1024 * 1024, encW1tL + (size_t)bi * 1024 * 1024, 0,
          encB1 + bi * 1024, 0, nullptr, nullptr, 0, nullptr, tH, tL, 0,
          nullptr, nullptr, Btok, 1024, 1024);
      gemm_bt<1, true, false><<<dim3(256), blk, 0, stream>>>(
          tH, tL, 0, encW2tH + (size_t)bi * 1024 * 1024, encW2tL + (size_t)bi * 1024 * 1024, 0,
          encB2 + bi * 1024, 0, rH, rL, 0, nullptr, hH, hL, 0,
          nullptr, nullptr, Btok, 1024, 1024);
      aH = hH; aL = hL; rH = hH; rL = hL;
    }
    gemm_bt<2, true, false><<<dim3(128), blk, 0, stream>>>(
        hH, hL, 0, encWftH, encWftL, 0, encBf, 0, nullptr, nullptr, 0,
        latF, latB, nullptr, 0, nullptr, nullptr, Btok, 512, 1024);
  }

  gate_topk<<<dim3(1024), blk, 0, stream>>>(latF, wgate, perm, cnt, tokES, tokG);

  // --- experts (sparse: gathered A / early-exit by cnt) ---
  {
    const size_t sW1 = (size_t)512 * 1024, sW2 = (size_t)1024 * 512;
    const size_t sTe = (size_t)CAP * 1024, sHe = (size_t)CAP * 512;
    for (int bi = 0; bi < 3; ++bi) {
      if (bi == 0) {
        gemm_bt<3, false, true><<<dim3(2048), blk, 0, stream>>>(
            latB, nullptr, 0, expW1t + bi * sW1, nullptr, 3 * sW1,
            expB1 + bi * 1024, 3 * 1024, nullptr, nullptr, 0, nullptr, Te, nullptr, sTe,
            perm, cnt, CAP, 1024, 512);
        gemm_bt<5, false, false><<<dim3(1024), blk, 0, stream>>>(
            Te, nullptr, sTe, expW2t + bi * sW2, nullptr, 3 * sW2,
            expB2 + bi * 512, 3 * 512, latB, nullptr, 0, nullptr, He, nullptr, sHe,
            perm, cnt, CAP, 512, 1024);
      } else {
        gemm_bt<3, false, false><<<dim3(2048), blk, 0, stream>>>(
            He, nullptr, sHe, expW1t + bi * sW1, nullptr, 3 * sW1,
            expB1 + bi * 1024, 3 * 1024, nullptr, nullptr, 0, nullptr, Te, nullptr, sTe,
            perm, cnt, CAP, 1024, 512);
        gemm_bt<4, false, false><<<dim3(1024), blk, 0, stream>>>(
            Te, nullptr, sTe, expW2t + bi * sW2, nullptr, 3 * sW2,
            expB2 + bi * 512, 3 * 512, He, nullptr, sHe, nullptr, He, nullptr, sHe,
            perm, cnt, CAP, 512, 1024);
      }
    }
  }
  combine_out<<<dim3(1024), blk, 0, stream>>>(He, expWf, expBf, tokES, tokG, (float*)d_out);

  // --- value head (plain bf16) ---
  {
    const bf16 *av = obsH, *resV = obsH;
    for (int bi = 0; bi < 3; ++bi) {
      gemm_bt<3, false, false><<<dim3(256), blk, 0, stream>>>(
          av, nullptr, 0, valW1t + (size_t)bi * 1024 * 1024, nullptr, 0,
          valB1 + bi * 1024, 0, nullptr, nullptr, 0, nullptr, tH, nullptr, 0,
          nullptr, nullptr, Btok, 1024, 1024);
      gemm_bt<4, false, false><<<dim3(256), blk, 0, stream>>>(
          tH, nullptr, 0, valW2t + (size_t)bi * 1024 * 1024, nullptr, 0,
          valB2 + bi * 1024, 0, resV, nullptr, 0, nullptr, hH, nullptr, 0,
          nullptr, nullptr, Btok, 1024, 1024);
      av = hH; resV = hH;
    }
    value_out<<<dim3(1024), blk, 0, stream>>>(hH, valWf, valBf, (float*)d_out);
  }
}

// Round 3
// 760.652 us; speedup vs baseline: 1.5256x; 1.3426x over previous
//
#include <hip/hip_runtime.h>
#include <hip/hip_bf16.h>
#include <stdint.h>
#include <stddef.h>

typedef __hip_bfloat16 bf16;
typedef __attribute__((ext_vector_type(8))) short short8;
typedef __attribute__((ext_vector_type(4))) float f32x4;

#define GLDS16(g, l) __builtin_amdgcn_global_load_lds( \
    (const __attribute__((address_space(1))) void*)(g), \
    (__attribute__((address_space(3))) void*)(l), 16, 0, 0)

__device__ __forceinline__ float bf2f(bf16 x) { return __bfloat162float(x); }
__device__ __forceinline__ bf16  f2bf(float x) { return __float2bfloat16(x); }

constexpr int CAP = 4096;

// ================= weight convert + transpose: src [K][N] f32 -> dst [N][K] bf16 (hi[,lo]) ===============
template<bool SPLIT>
__global__ void wconv(const float* __restrict__ src, bf16* __restrict__ dhi,
                      bf16* __restrict__ dlo, int K, int N) {
  __shared__ float tile[32][33];
  const size_t zoff = (size_t)blockIdx.z * K * N;
  const float* s = src + zoff;
  const int n0 = blockIdx.x * 32, k0 = blockIdx.y * 32;
  const int tx = threadIdx.x & 31, ty = threadIdx.x >> 5;
#pragma unroll
  for (int i = 0; i < 32; i += 8)
    tile[ty + i][tx] = s[(size_t)(k0 + ty + i) * N + (n0 + tx)];
  __syncthreads();
#pragma unroll
  for (int i = 0; i < 32; i += 8) {
    const float v = tile[tx][ty + i];
    const size_t o = zoff + (size_t)(n0 + ty + i) * K + (k0 + tx);
    const bf16 h = f2bf(v);
    dhi[o] = h;
    if (SPLIT) dlo[o] = f2bf(v - bf2f(h));
  }
}

// ================= elementwise f32 -> bf16 hi/lo split =================
__global__ void splitv(const float* __restrict__ x, bf16* __restrict__ hi,
                       bf16* __restrict__ lo, int n4) {
  const int i = blockIdx.x * 256 + threadIdx.x;
  if (i >= n4) return;
  const float4 v = ((const float4*)x)[i];
  const float f[4] = {v.x, v.y, v.z, v.w};
#pragma unroll
  for (int j = 0; j < 4; ++j) {
    const bf16 h = f2bf(f[j]);
    hi[i * 4 + j] = h;
    lo[i * 4 + j] = f2bf(f[j] - bf2f(h));
  }
}

// ================= core 128x128 tile GEMM body =================
// EPI: 0 relu -> (Ch,Cl)            1 +bias +Rh+Rl -> (Ch,Cl)
//      3 relu -> Ch                 4 +bias +Rb -> Ch
//      5 +bias +Rb(perm-gathered rows) -> Ch
//      6 raw f32 partial -> Cf (split-K, no bias)
template<int EPI, bool SPLIT, bool GATHER>
__device__ __forceinline__ void gemm_tile(
    const bf16* __restrict__ Ah, const bf16* __restrict__ Al,
    const bf16* __restrict__ Bh, const bf16* __restrict__ Bl,
    const float* __restrict__ bias,
    const bf16* __restrict__ Rb, const bf16* __restrict__ Rl2,
    float* __restrict__ Cf, bf16* __restrict__ Ch, bf16* __restrict__ Cl,
    const int* __restrict__ permz, int cE,
    int bx, int by, int N, int K, int lda, int kbase,
    bf16* As, bf16* Bs) {
  const int tid = threadIdx.x, lane = tid & 63, wave = tid >> 6;
  const int wr = wave >> 1, wc = wave & 1;
  const int fr = lane & 15, q = lane >> 4, fq = q << 2;

  int arow[4], brow[4];
#pragma unroll
  for (int i = 0; i < 4; ++i) {
    const int r = (i * 256 + tid) >> 3;
    const int slot = bx * 128 + r;
    arow[i] = GATHER ? ((slot < cE) ? permz[slot] : 0) : slot;
    brow[i] = by * 128 + r;
  }

  f32x4 acc[4][4];
#pragma unroll
  for (int m = 0; m < 4; ++m)
#pragma unroll
    for (int n = 0; n < 4; ++n) {
      acc[m][n][0] = 0.f; acc[m][n][1] = 0.f; acc[m][n][2] = 0.f; acc[m][n][3] = 0.f;
    }

  const int nk = K >> 6;
  for (int kt = 0; kt < nk; ++kt) {
    const int k0 = kbase + (kt << 6);
#pragma unroll
    for (int i = 0; i < 4; ++i) {
      const int ci = i * 256 + tid;
      const int r = ci >> 3, pch = ci & 7;
      const int c = pch ^ (r & 7);                  // inverse-swizzled global chunk
      const size_t ga = (size_t)arow[i] * lda + k0 + c * 8;
      const size_t gb = (size_t)brow[i] * lda + k0 + c * 8;
      GLDS16(Ah + ga, As + ci * 8);
      GLDS16(Bh + gb, Bs + ci * 8);
      if (SPLIT) {
        GLDS16(Al + ga, As + 8192 + ci * 8);
        GLDS16(Bl + gb, Bs + 8192 + ci * 8);
      }
    }
    __syncthreads();

#pragma unroll
    for (int kk = 0; kk < 2; ++kk) {
      auto LD = [&](const bf16* base, int r) -> short8 {
        const int c = ((kk << 2) + q) ^ (r & 7);
        return *(const short8*)(base + r * 64 + c * 8);
      };
      short8 a0[4], b0[4];
#pragma unroll
      for (int m = 0; m < 4; ++m) a0[m] = LD(As, wr * 64 + m * 16 + fr);
#pragma unroll
      for (int n = 0; n < 4; ++n) b0[n] = LD(Bs, wc * 64 + n * 16 + fr);
      if (SPLIT) {
        short8 a1[4], b1[4];
#pragma unroll
        for (int m = 0; m < 4; ++m) a1[m] = LD(As + 8192, wr * 64 + m * 16 + fr);
#pragma unroll
        for (int n = 0; n < 4; ++n) b1[n] = LD(Bs + 8192, wc * 64 + n * 16 + fr);
#pragma unroll
        for (int m = 0; m < 4; ++m)
#pragma unroll
          for (int n = 0; n < 4; ++n) {
            acc[m][n] = __builtin_amdgcn_mfma_f32_16x16x32_bf16(a1[m], b0[n], acc[m][n], 0, 0, 0);
            acc[m][n] = __builtin_amdgcn_mfma_f32_16x16x32_bf16(a0[m], b1[n], acc[m][n], 0, 0, 0);
          }
      }
#pragma unroll
      for (int m = 0; m < 4; ++m)
#pragma unroll
        for (int n = 0; n < 4; ++n)
          acc[m][n] = __builtin_amdgcn_mfma_f32_16x16x32_bf16(a0[m], b0[n], acc[m][n], 0, 0, 0);
    }
    __syncthreads();
  }

#pragma unroll
  for (int n = 0; n < 4; ++n) {
    const int col = by * 128 + wc * 64 + n * 16 + fr;
    const float bv = (EPI == 6) ? 0.f : bias[col];
#pragma unroll
    for (int m = 0; m < 4; ++m) {
      const int row0 = bx * 128 + wr * 64 + m * 16 + fq;
#pragma unroll
      for (int r = 0; r < 4; ++r) {
        const int rowi = row0 + r;
        const size_t o = (size_t)rowi * N + col;
        float v = acc[m][n][r] + bv;
        if (EPI == 0 || EPI == 3) v = fmaxf(v, 0.f);
        if (EPI == 1) v += bf2f(Rb[o]) + bf2f(Rl2[o]);
        if (EPI == 4) v += bf2f(Rb[o]);
        if (EPI == 5) {
          const int rr = (rowi < cE) ? permz[rowi] : 0;
          v += bf2f(Rb[(size_t)rr * N + col]);
        }
        if (EPI == 6) {
          Cf[o] = v;
        } else {
          const bf16 h = f2bf(v);
          Ch[o] = h;
          if (EPI == 0 || EPI == 1) Cl[o] = f2bf(v - bf2f(h));
        }
      }
    }
  }
}

// ================= single GEMM (experts / split-K final) ===============
template<int EPI, bool SPLIT, bool GATHER, bool SPLITK>
__global__ __launch_bounds__(256, 2)
void gemm_bt(const bf16* __restrict__ Ah, const bf16* __restrict__ Al, size_t aSz,
             const bf16* __restrict__ Bh, const bf16* __restrict__ Bl, size_t bSz,
             const float* __restrict__ bias, size_t biasSz,
             const void* __restrict__ R, size_t rSz,
             float* __restrict__ Cf, bf16* __restrict__ Ch, bf16* __restrict__ Cl, size_t cSz,
             const int* __restrict__ perm, const int* __restrict__ cnt,
             int M, int N, int K, int lda) {
  __shared__ __align__(16) bf16 As[(SPLIT ? 2 : 1) * 8192];
  __shared__ __align__(16) bf16 Bs[(SPLIT ? 2 : 1) * 8192];
  const int gx = M >> 7, gy = N >> 7, nwg = gridDim.x, lid = blockIdx.x;
  const int wid = (lid & 7) * (nwg >> 3) + (lid >> 3);
  const int by = wid % gy, bx = (wid / gy) % gx, bz = wid / (gy * gx);

  int cE = 0x7fffffff;
  if (cnt) { cE = cnt[bz]; if (bx * 128 >= cE) return; }

  Ah += (size_t)bz * aSz;
  Bh += (size_t)bz * bSz;
  if (SPLIT) { Al += (size_t)bz * aSz; Bl += (size_t)bz * bSz; }
  if (bias) bias += (size_t)bz * biasSz;
  const bf16* Rb = (const bf16*)R;
  if (EPI == 4) Rb += (size_t)bz * rSz;
  if (EPI == 6) Cf += (size_t)bz * cSz; else Ch += (size_t)bz * cSz;
  const int* permz = perm ? (perm + (size_t)bz * CAP) : nullptr;
  const int kbase = SPLITK ? bz * K : 0;

  gemm_tile<EPI, SPLIT, GATHER>(Ah, Al, Bh, Bl, bias, Rb, nullptr, Cf, Ch, Cl,
                                permz, cE, bx, by, N, K, lda, kbase, As, Bs);
}

// ================= dual GEMM: z=0 split(enc), z=1 plain(value), z interleaved lowest bit ===============
template<int EPI0, int EPI1>
__global__ __launch_bounds__(256, 2)
void gemm_dual(const bf16* __restrict__ Ah, const bf16* __restrict__ Al,
               const bf16* __restrict__ B0h, const bf16* __restrict__ B0l,
               const float* __restrict__ bias0,
               const bf16* __restrict__ R0h, const bf16* __restrict__ R0l,
               bf16* __restrict__ C0h, bf16* __restrict__ C0l,
               const bf16* __restrict__ A1, const bf16* __restrict__ B1,
               const float* __restrict__ bias1, const bf16* __restrict__ R1,
               bf16* __restrict__ C1,
               int M, int N, int K) {
  __shared__ __align__(16) bf16 As[2 * 8192];
  __shared__ __align__(16) bf16 Bs[2 * 8192];
  const int gy = N >> 7, nwg = gridDim.x, lid = blockIdx.x;
  const int wid = (lid & 7) * (nwg >> 3) + (lid >> 3);
  const int z = wid & 1, w2 = wid >> 1;
  const int by = w2 % gy, bx = w2 / gy;
  if (z == 0)
    gemm_tile<EPI0, true, false>(Ah, Al, B0h, B0l, bias0, R0h, R0l, nullptr, C0h, C0l,
                                 nullptr, 0x7fffffff, bx, by, N, K, K, 0, As, Bs);
  else
    gemm_tile<EPI1, false, false>(A1, nullptr, B1, nullptr, bias1, R1, nullptr, nullptr, C1, nullptr,
                                  nullptr, 0x7fffffff, bx, by, N, K, K, 0, As, Bs);
}

// ================= gate: latent = P0+P1+bias; logits; top-2; writes latB ===============
__global__ void gate_logits(const float* __restrict__ P0, const float* __restrict__ P1,
                            const float* __restrict__ bfv, const float* __restrict__ wg,
                            bf16* __restrict__ latB, int* __restrict__ tokE,
                            float2* __restrict__ tokG) {
  __shared__ float wgs[8 * 512];   // [e][k]
  __shared__ float bfs[512];
  const int tid = threadIdx.x;
  for (int i = tid; i < 4096; i += 256) wgs[(i & 7) * 512 + (i >> 3)] = wg[i];
  for (int i = tid; i < 512; i += 256) bfs[i] = bfv[i];
  __syncthreads();
  const int lane = tid & 63, wv = tid >> 6;
#pragma unroll 1
  for (int tt = 0; tt < 4; ++tt) {
    const int t = blockIdx.x * 16 + wv * 4 + tt;
    float lv[8];
    float le[8] = {0.f, 0.f, 0.f, 0.f, 0.f, 0.f, 0.f, 0.f};
#pragma unroll
    for (int j = 0; j < 8; ++j) {
      const int k = lane + 64 * j;
      lv[j] = P0[(size_t)t * 512 + k] + P1[(size_t)t * 512 + k] + bfs[k];
      latB[(size_t)t * 512 + k] = f2bf(lv[j]);
#pragma unroll
      for (int e = 0; e < 8; ++e) le[e] = fmaf(lv[j], wgs[e * 512 + k], le[e]);
    }
#pragma unroll
    for (int e = 0; e < 8; ++e) {
#pragma unroll
      for (int d = 32; d > 0; d >>= 1) le[e] += __shfl_down(le[e], d);
    }
    if (lane == 0) {
      int i1 = 0; float v1 = le[0];
#pragma unroll
      for (int e = 1; e < 8; ++e) if (le[e] > v1) { v1 = le[e]; i1 = e; }
      int i2 = -1; float v2 = -3.4e38f;
#pragma unroll
      for (int e = 0; e < 8; ++e) if (e != i1 && le[e] > v2) { v2 = le[e]; i2 = e; }
      const float e2 = expf(v2 - v1);
      const float inv = 1.f / (1.f + e2);
      tokE[t] = i1 | (i2 << 8);
      tokG[t] = make_float2(inv, e2 * inv);
    }
  }
}

// ================= deterministic compaction: per-expert token lists + slots ===============
__global__ void gate_compact(const int* __restrict__ tokE, int* __restrict__ perm,
                             int* __restrict__ cnt, int* __restrict__ slot1,
                             int* __restrict__ slot2) {
  const int e = blockIdx.x;
  __shared__ int wsum[4];
  __shared__ int sbase;
  if (threadIdx.x == 0) sbase = 0;
  __syncthreads();
  const int lane = threadIdx.x & 63, wv = threadIdx.x >> 6;
  for (int c0 = 0; c0 < 4096; c0 += 256) {
    const int t = c0 + threadIdx.x;
    const int te = tokE[t];
    const int which = ((te & 255) == e) ? 0 : ((((te >> 8) & 255) == e) ? 1 : -1);
    const unsigned long long m = __ballot(which >= 0);
    if (lane == 0) wsum[wv] = __popcll(m);
    __syncthreads();
    int off = sbase;
    for (int w = 0; w < wv; ++w) off += wsum[w];
    if (which >= 0) {
      const int slot = off + __popcll(m & ((1ull << lane) - 1ull));
      perm[e * CAP + slot] = t;
      if (which == 0) slot1[t] = slot; else slot2[t] = slot;
    }
    __syncthreads();
    if (threadIdx.x == 0) sbase += wsum[0] + wsum[1] + wsum[2] + wsum[3];
    __syncthreads();
  }
  if (threadIdx.x == 0) cnt[e] = sbase;
}

// ================= combine ===============
__global__ void combine_out(const bf16* __restrict__ He, const float* __restrict__ Wf,
                            const float* __restrict__ Bf, const int* __restrict__ tokE,
                            const float2* __restrict__ tokG, const int* __restrict__ slot1,
                            const int* __restrict__ slot2, float* __restrict__ out) {
  const int b = blockIdx.x * 4 + (threadIdx.x >> 6);
  const int lane = threadIdx.x & 63;
  const int te = tokE[b];
  const float2 gg = tokG[b];
  const int ee[2] = {te & 255, (te >> 8) & 255};
  const int sl[2] = {slot1[b], slot2[b]};
  const float gv[2] = {gg.x, gg.y};
  float y[19];
#pragma unroll
  for (int o = 0; o < 19; ++o) y[o] = 0.f;
#pragma unroll
  for (int t = 0; t < 2; ++t) {
    const bf16* h = He + ((size_t)ee[t] * CAP + sl[t]) * 512;
    float part[19];
#pragma unroll
    for (int o = 0; o < 19; ++o) part[o] = 0.f;
    for (int k = lane; k < 512; k += 64) {
      const float hv = bf2f(h[k]);
      const float* w = Wf + ((size_t)ee[t] * 512 + k) * 19;
#pragma unroll
      for (int o = 0; o < 19; ++o) part[o] = fmaf(hv, w[o], part[o]);
    }
#pragma unroll
    for (int o = 0; o < 19; ++o) y[o] = fmaf(gv[t], part[o], y[o]);
  }
#pragma unroll
  for (int o = 0; o < 19; ++o) {
#pragma unroll
    for (int d = 32; d > 0; d >>= 1) y[o] += __shfl_down(y[o], d);
  }
  if (lane == 0) {
#pragma unroll
    for (int o = 0; o < 19; ++o) {
      float v = y[o] + gg.x * Bf[ee[0] * 19 + o] + gg.y * Bf[ee[1] * 19 + o];
      if (v == 0.f) v = 2.2204460492503131e-16f;
      out[(size_t)b * 20 + o] = v;
    }
  }
}

// ================= value head ===============
__global__ void value_out(const bf16* __restrict__ Hv, const float* __restrict__ Wf,
                          const float* __restrict__ Bf, float* __restrict__ out) {
  const int b = blockIdx.x * 4 + (threadIdx.x >> 6);
  const int lane = threadIdx.x & 63;
  const bf16* h = Hv + (size_t)b * 1024;
  float s = 0.f;
  for (int k = lane; k < 1024; k += 64) s = fmaf(bf2f(h[k]), Wf[k], s);
#pragma unroll
  for (int d = 32; d > 0; d >>= 1) s += __shfl_down(s, d);
  if (lane == 0) out[(size_t)b * 20 + 19] = s + Bf[0];
}

// ================= host =================
extern "C" void kernel_launch(void* const* d_in, const int* in_sizes, int n_in,
                              void* d_out, int out_size, void* d_ws, size_t ws_size,
                              hipStream_t stream) {
  (void)in_sizes; (void)n_in; (void)out_size; (void)ws_size;
  const int Btok = 4096;

  const float* obs   = (const float*)d_in[0];
  const float* encW1 = (const float*)d_in[1];
  const float* encB1 = (const float*)d_in[2];
  const float* encW2 = (const float*)d_in[3];
  const float* encB2 = (const float*)d_in[4];
  const float* encWf = (const float*)d_in[5];
  const float* encBf = (const float*)d_in[6];
  const float* expW1 = (const float*)d_in[7];
  const float* expB1 = (const float*)d_in[8];
  const float* expW2 = (const float*)d_in[9];
  const float* expB2 = (const float*)d_in[10];
  const float* expWf = (const float*)d_in[11];
  const float* expBf = (const float*)d_in[12];
  const float* valW1 = (const float*)d_in[13];
  const float* valB1 = (const float*)d_in[14];
  const float* valW2 = (const float*)d_in[15];
  const float* valB2 = (const float*)d_in[16];
  const float* valWf = (const float*)d_in[17];
  const float* valBf = (const float*)d_in[18];
  const float* wgate = (const float*)d_in[19];

  char* p = (char*)d_ws;
  auto alloc = [&](size_t bytes) -> char* {
    char* r = p; p += (bytes + 255) & ~(size_t)255; return r;
  };
  // weights (bf16, transposed [N][K])
  bf16* encW1tH = (bf16*)alloc((size_t)3 * 1024 * 1024 * 2);
  bf16* encW1tL = (bf16*)alloc((size_t)3 * 1024 * 1024 * 2);
  bf16* encW2tH = (bf16*)alloc((size_t)3 * 1024 * 1024 * 2);
  bf16* encW2tL = (bf16*)alloc((size_t)3 * 1024 * 1024 * 2);
  bf16* encWftH = (bf16*)alloc((size_t)512 * 1024 * 2);
  bf16* encWftL = (bf16*)alloc((size_t)512 * 1024 * 2);
  bf16* valW1t  = (bf16*)alloc((size_t)3 * 1024 * 1024 * 2);
  bf16* valW2t  = (bf16*)alloc((size_t)3 * 1024 * 1024 * 2);
  bf16* expW1t  = (bf16*)alloc((size_t)24 * 512 * 1024 * 2);
  bf16* expW2t  = (bf16*)alloc((size_t)24 * 512 * 1024 * 2);
  // activations
  bf16*  obsH  = (bf16*)alloc((size_t)Btok * 1024 * 2);
  bf16*  tH    = (bf16*)alloc((size_t)Btok * 1024 * 2);
  bf16*  hH    = (bf16*)alloc((size_t)Btok * 1024 * 2);
  bf16*  vT    = (bf16*)alloc((size_t)Btok * 1024 * 2);
  bf16*  vH    = (bf16*)alloc((size_t)Btok * 1024 * 2);
  bf16*  latB  = (bf16*)alloc((size_t)Btok * 512 * 2);
  int*   perm  = (int*)alloc((size_t)8 * CAP * 4);
  int*   cnt   = (int*)alloc(8 * 4);
  int*   tokE  = (int*)alloc((size_t)Btok * 4);
  float2* tokG = (float2*)alloc((size_t)Btok * 8);
  int*   slot1 = (int*)alloc((size_t)Btok * 4);
  int*   slot2 = (int*)alloc((size_t)Btok * 4);
  // He region (32 MiB): also hosts enc-only low/residual temporaries (dead before expert writes)
  char* heR = alloc((size_t)8 * CAP * 512 * 2);
  bf16* He   = (bf16*)heR;
  bf16* tL   = (bf16*)heR;                                   // dead after last dual-G2
  bf16* hL   = (bf16*)(heR + (size_t)Btok * 1024 * 2);       // dead after final enc GEMM
  bf16* obsL = (bf16*)(heR + (size_t)2 * Btok * 1024 * 2);   // dead after dual-G2 bi=0
  // Te region (64 MiB): hosts split-K partials P0/P1 (dead before expert G1 writes Te)
  char* teR = alloc((size_t)8 * CAP * 1024 * 2);
  bf16*  Te = (bf16*)teR;
  float* P0 = (float*)teR;
  float* P1 = P0 + (size_t)Btok * 512;

  const dim3 blk(256);

  // --- conversions ---
  splitv<<<dim3((Btok * 1024 / 4 + 255) / 256), blk, 0, stream>>>(obs, obsH, obsL, Btok * 1024 / 4);
  wconv<true ><<<dim3(32, 32, 3),  blk, 0, stream>>>(encW1, encW1tH, encW1tL, 1024, 1024);
  wconv<true ><<<dim3(32, 32, 3),  blk, 0, stream>>>(encW2, encW2tH, encW2tL, 1024, 1024);
  wconv<true ><<<dim3(16, 32, 1),  blk, 0, stream>>>(encWf, encWftH, encWftL, 1024, 512);
  wconv<false><<<dim3(32, 32, 3),  blk, 0, stream>>>(valW1, valW1t, nullptr, 1024, 1024);
  wconv<false><<<dim3(32, 32, 3),  blk, 0, stream>>>(valW2, valW2t, nullptr, 1024, 1024);
  wconv<false><<<dim3(32, 16, 24), blk, 0, stream>>>(expW1, expW1t, nullptr, 512, 1024);
  wconv<false><<<dim3(16, 32, 24), blk, 0, stream>>>(expW2, expW2t, nullptr, 1024, 512);

  // --- encoder (split) + value (plain) fused dual GEMMs, 512 blocks = 2/CU ---
  {
    const bf16 *aH = obsH, *aL = obsL, *rH = obsH, *rL = obsL;
    const bf16 *av = obsH, *rv = obsH;
    for (int bi = 0; bi < 3; ++bi) {
      gemm_dual<0, 3><<<dim3(512), blk, 0, stream>>>(
          aH, aL, encW1tH + (size_t)bi * 1024 * 1024, encW1tL + (size_t)bi * 1024 * 1024,
          encB1 + bi * 1024, nullptr, nullptr, tH, tL,
          av, valW1t + (size_t)bi * 1024 * 1024, valB1 + bi * 1024, nullptr, vT,
          Btok, 1024, 1024);
      gemm_dual<1, 4><<<dim3(512), blk, 0, stream>>>(
          tH, tL, encW2tH + (size_t)bi * 1024 * 1024, encW2tL + (size_t)bi * 1024 * 1024,
          encB2 + bi * 1024, rH, rL, hH, hL,
          vT, valW2t + (size_t)bi * 1024 * 1024, valB2 + bi * 1024, rv, vH,
          Btok, 1024, 1024);
      aH = hH; aL = hL; rH = hH; rL = hL;
      av = vH; rv = vH;
    }
  }

  // --- final enc GEMM: split-K=2 -> f32 partials ---
  gemm_bt<6, true, false, true><<<dim3(256), blk, 0, stream>>>(
      hH, hL, 0, encWftH, encWftL, 0, nullptr, 0, nullptr, 0,
      P0, nullptr, nullptr, (size_t)Btok * 512, nullptr, nullptr,
      Btok, 512, 512, 1024);

  // --- gating ---
  gate_logits<<<dim3(256), blk, 0, stream>>>(P0, P1, encBf, wgate, latB, tokE, tokG);
  gate_compact<<<dim3(8), blk, 0, stream>>>(tokE, perm, cnt, slot1, slot2);

  // --- experts (sparse) ---
  {
    const size_t sW1 = (size_t)512 * 1024, sW2 = (size_t)1024 * 512;
    const size_t sTe = (size_t)CAP * 1024, sHe = (size_t)CAP * 512;
    for (int bi = 0; bi < 3; ++bi) {
      if (bi == 0) {
        gemm_bt<3, false, true, false><<<dim3(2048), blk, 0, stream>>>(
            latB, nullptr, 0, expW1t + bi * sW1, nullptr, 3 * sW1,
            expB1 + bi * 1024, 3 * 1024, nullptr, 0, nullptr, Te, nullptr, sTe,
            perm, cnt, CAP, 1024, 512, 512);
        gemm_bt<5, false, false, false><<<dim3(1024), blk, 0, stream>>>(
            Te, nullptr, sTe, expW2t + bi * sW2, nullptr, 3 * sW2,
            expB2 + bi * 512, 3 * 512, latB, 0, nullptr, He, nullptr, sHe,
            perm, cnt, CAP, 512, 1024, 1024);
      } else {
        gemm_bt<3, false, false, false><<<dim3(2048), blk, 0, stream>>>(
            He, nullptr, sHe, expW1t + bi * sW1, nullptr, 3 * sW1,
            expB1 + bi * 1024, 3 * 1024, nullptr, 0, nullptr, Te, nullptr, sTe,
            perm, cnt, CAP, 1024, 512, 512);
        gemm_bt<4, false, false, false><<<dim3(1024), blk, 0, stream>>>(
            Te, nullptr, sTe, expW2t + bi * sW2, nullptr, 3 * sW2,
            expB2 + bi * 512, 3 * 512, He, sHe, nullptr, He, nullptr, sHe,
            perm, cnt, CAP, 512, 1024, 1024);
      }
    }
  }
  combine_out<<<dim3(1024), blk, 0, stream>>>(He, expWf, expBf, tokE, tokG, slot1, slot2,
                                              (float*)d_out);
  value_out<<<dim3(1024), blk, 0, stream>>>(vH, valWf, valBf, (float*)d_out);
}